// Round 19
// baseline (299.605 us; speedup 1.0000x reference)
//
#include <hip/hip_runtime.h>
#include <hip/hip_bf16.h>

// Transformer block: B=4 T=2048 C=384 H=6 HS=64.
// Reference softmax is over the QUERY axis -> w[t,s] = exp(S[t,s])/colsum[s],
// colsum[s] = sum_{t>=s} exp(S[t,s]).  Pipeline: colsum pass, then out = E @ V
// with the colsum division folded into the exponent:
//   E = exp(S*SCALE - log(colsum[s]))   (R19 — removes the per-element rc mul).
//
// R19 = R18 with two attn VALU trims (all else byte-identical):
//  - log-space normalization (LDS table holds log(colsum), mul folds into mad);
//  - wave-uniform causal-mask skip for tiles strictly below the diagonal.
// R17/R18 established: gemm128 register prefetch pays (<~2 blocks/CU); attn
// prefetch does not (6 blocks/CU, TLP already hides staging).
// WS total 28,803,072 B (proven footprint).

#define BB 4
#define TT 2048
#define CC 384
#define HH 6
#define HS 64
#define BT 8192
#define C4 1536
#define VST 2080              // padded V^T leading dim (elements): 4160B rows
#define SCALE 0.05103103630798288f   // 384^-0.5

typedef __attribute__((ext_vector_type(8))) short short8;   // 8 x bf16
typedef __attribute__((ext_vector_type(4))) float f32x4;
typedef __hip_bfloat16 bf16_t;

__device__ inline short8 ld8(const bf16_t* p) { return *reinterpret_cast<const short8*>(p); }
__device__ inline float tof(float v) { return v; }
__device__ inline float tof(bf16_t v) { return __bfloat162float(v); }
__device__ inline short8 cv8(const float* p) {
    f32x4 lo = *(const f32x4*)p;
    f32x4 hi = *(const f32x4*)(p + 4);
    short8 r;
#pragma unroll
    for (int i = 0; i < 4; i++) {
        bf16_t a = __float2bfloat16(lo[i]);
        bf16_t b = __float2bfloat16(hi[i]);
        r[i]     = *reinterpret_cast<short*>(&a);
        r[i + 4] = *reinterpret_cast<short*>(&b);
    }
    return r;
}
#define MFMA(a, b, c) __builtin_amdgcn_mfma_f32_16x16x32_bf16(a, b, c, 0, 0, 0)

// ---------------- zero-init ----------------
__global__ __launch_bounds__(256) void zinit_kernel(float* __restrict__ p, int n4) {
    int i = blockIdx.x * 256 + threadIdx.x;
    if (i < n4) ((f32x4*)p)[i] = (f32x4){0.f, 0.f, 0.f, 0.f};
}

// ---------------- prep: LDS-tiled 64x64 transposes (R16-proven) + attn_f zero ----------------
#define RW  147456          // per qkv matrix element count (6 heads x 384 x 64)
__global__ __launch_bounds__(256) void prep_kernel(const float* __restrict__ wq,
                                                   const float* __restrict__ wk,
                                                   const float* __restrict__ wv,
                                                   const float* __restrict__ wproj,
                                                   const float* __restrict__ w1,
                                                   const float* __restrict__ w2,
                                                   bf16_t* __restrict__ wall,   // wqt|wkt|wvt
                                                   bf16_t* __restrict__ wpt,
                                                   bf16_t* __restrict__ w1t,
                                                   bf16_t* __restrict__ w2t,
                                                   float* __restrict__ attnf) {
    int id = blockIdx.x;
    int tid = threadIdx.x;
    if (id >= 432) {                       // zero range: 192 blocks
        int base = (id - 432) * 256 + tid; // 0..49151
        f32x4 z = {0.f, 0.f, 0.f, 0.f};
#pragma unroll
        for (int k = 0; k < 16; k++)
            ((f32x4*)attnf)[base + k * 49152] = z;
        return;
    }
    const float* src; bf16_t* dst; int R, C, t;
    if (id < 108) {                        // wq/wk/wv: per head R=384, C=64
        int m = id / 36, r = id - m * 36;
        src = (m == 0 ? wq : (m == 1 ? wk : wv));
        dst = wall + m * RW;
        int b = r / 6; t = r - b * 6;
        src += b * 24576; dst += b * 24576;
        R = 384; C = 64;
    } else if (id < 144) { src = wproj; dst = wpt; t = id - 108; R = 384;  C = 384; }
    else if (id < 288)   { src = w1;    dst = w1t; t = id - 144; R = 384;  C = 1536; }
    else                 { src = w2;    dst = w2t; t = id - 288; R = 1536; C = 384; }
    int tiles_r = R >> 6;
    int tr = t % tiles_r, tc = t / tiles_r;
    __shared__ float Tsh[64][65];
    const int rr = tid >> 4;               // 0..15
    const int cc = (tid & 15) * 4;         // 0..60
#pragma unroll
    for (int i = 0; i < 4; i++) {
        int row = tr * 64 + rr + i * 16;
        f32x4 v = *(const f32x4*)(src + (size_t)row * C + tc * 64 + cc);
#pragma unroll
        for (int j = 0; j < 4; j++) Tsh[rr + i * 16][cc + j] = v[j];
    }
    __syncthreads();
#pragma unroll
    for (int i = 0; i < 4; i++) {
        int cl = rr + i * 16;              // out-row (n) local index
        ushort4 o;
        bf16_t b0 = __float2bfloat16(Tsh[cc + 0][cl]);
        bf16_t b1 = __float2bfloat16(Tsh[cc + 1][cl]);
        bf16_t b2v = __float2bfloat16(Tsh[cc + 2][cl]);
        bf16_t b3 = __float2bfloat16(Tsh[cc + 3][cl]);
        o.x = *reinterpret_cast<unsigned short*>(&b0);
        o.y = *reinterpret_cast<unsigned short*>(&b1);
        o.z = *reinterpret_cast<unsigned short*>(&b2v);
        o.w = *reinterpret_cast<unsigned short*>(&b3);
        *(ushort4*)(dst + (size_t)(tc * 64 + cl) * R + tr * 64 + cc) = o;
    }
}

// ---------------- LayerNorm: one wave per row of 384; input fp32 or bf16 ----------------
// INIT: also write oinit[m][c] = bias2[c] + raw x value (mlp2 split-K base).
template <typename T, bool INIT>
__global__ __launch_bounds__(256) void ln_kernel(const T* __restrict__ x,
                                                 const float* __restrict__ g,
                                                 const float* __restrict__ be,
                                                 bf16_t* __restrict__ out,
                                                 const float* __restrict__ bias2,
                                                 float* __restrict__ oinit) {
    int wave = threadIdx.x >> 6, lane = threadIdx.x & 63;
    int row = blockIdx.x * 4 + wave;
    const T* xr = x + (size_t)row * CC;
    float v[6];
    float s = 0.f;
#pragma unroll
    for (int i = 0; i < 6; i++) { v[i] = tof(xr[lane + i * 64]); s += v[i]; }
#pragma unroll
    for (int off = 32; off > 0; off >>= 1) s += __shfl_xor(s, off, 64);
    float mean = s * (1.f / 384.f);
    float s2 = 0.f;
#pragma unroll
    for (int i = 0; i < 6; i++) { float d = v[i] - mean; s2 += d * d; }
#pragma unroll
    for (int off = 32; off > 0; off >>= 1) s2 += __shfl_xor(s2, off, 64);
    float rstd = rsqrtf(s2 * (1.f / 384.f) + 1e-5f);
    bf16_t* orow = out + (size_t)row * CC;
#pragma unroll
    for (int i = 0; i < 6; i++) {
        int c = lane + i * 64;
        orow[c] = __float2bfloat16((v[i] - mean) * rstd * g[c] + be[c]);
        if constexpr (INIT) oinit[(size_t)row * CC + c] = bias2[c] + v[i];
    }
}

// ---------------- 128x128-tile GEMM, LDS-staged, software-pipelined (R17-proven). ----------------
// EPI: 0 = +bias +fp32 resid -> bf16; 1 = +bias relu -> bf16; 2 = +bias +bf16 resid -> fp32;
//      3 = qkv scatter; 4 = split-K: blockIdx.z picks K range [z*KDIM/4, +KDIM/4), fp32 atomicAdd.
template <int KDIM, int EPI, bool AF32 = false>
__global__ __launch_bounds__(256) void gemm128_kernel(const void* __restrict__ A,
                                                      const bf16_t* __restrict__ Bt,
                                                      const float* __restrict__ bias,
                                                      const void* __restrict__ resid,
                                                      void* __restrict__ o0,
                                                      void* __restrict__ o1,
                                                      void* __restrict__ o2, int N) {
    const int m0 = blockIdx.x * 128, n0 = blockIdx.y * 128;
    const int tid = threadIdx.x;
    const int lane = tid & 63, wave = tid >> 6;
    const int r16 = lane & 15, quad = lane >> 4;
    const int wm = (wave >> 1) * 64, wn = (wave & 1) * 64;
    __shared__ bf16_t Ash[128][40];
    __shared__ bf16_t Bsh[128][40];
    f32x4 zero = {0.f, 0.f, 0.f, 0.f};
    f32x4 acc[4][4];
#pragma unroll
    for (int i = 0; i < 4; i++)
#pragma unroll
        for (int j = 0; j < 4; j++) acc[i][j] = zero;
    const int srow = tid >> 2;
    const int scol = (tid & 3) * 8;
    int kbeg = 0, kend = KDIM;
    if constexpr (EPI == 4) { kbeg = blockIdx.z * (KDIM / 4); kend = kbeg + KDIM / 4; }
    short8 a0, a1, b0, b1;
    auto loadAB = [&](int k0) {
        if constexpr (AF32) {
            const float* Ag = (const float*)A + (size_t)(m0 + srow) * KDIM + k0 + scol;
            a0 = cv8(Ag);
            a1 = cv8(Ag + (size_t)64 * KDIM);
        } else {
            const bf16_t* Ag = (const bf16_t*)A + (size_t)(m0 + srow) * KDIM + k0 + scol;
            a0 = ld8(Ag);
            a1 = ld8(Ag + (size_t)64 * KDIM);
        }
        const bf16_t* Bg = Bt + (size_t)(n0 + srow) * KDIM + k0 + scol;
        b0 = ld8(Bg);
        b1 = ld8(Bg + (size_t)64 * KDIM);
    };
    loadAB(kbeg);
    for (int k0 = kbeg; k0 < kend; k0 += 32) {
        *(short8*)&Ash[srow][scol]      = a0;
        *(short8*)&Ash[64 + srow][scol] = a1;
        *(short8*)&Bsh[srow][scol]      = b0;
        *(short8*)&Bsh[64 + srow][scol] = b1;
        __syncthreads();
        // prefetch next k-tile (clamped) — latency hidden behind the MFMA phase
        loadAB(k0 + 32 < kend ? k0 + 32 : kbeg);
        short8 af[4], bfr[4];
#pragma unroll
        for (int i = 0; i < 4; i++) af[i]  = *(const short8*)&Ash[wm + i * 16 + r16][quad * 8];
#pragma unroll
        for (int i = 0; i < 4; i++) bfr[i] = *(const short8*)&Bsh[wn + i * 16 + r16][quad * 8];
#pragma unroll
        for (int mi = 0; mi < 4; mi++)
#pragma unroll
            for (int ni = 0; ni < 4; ni++)
                acc[mi][ni] = MFMA(af[mi], bfr[ni], acc[mi][ni]);
        __syncthreads();
    }
#pragma unroll
    for (int mi = 0; mi < 4; mi++)
#pragma unroll
        for (int ni = 0; ni < 4; ni++)
#pragma unroll
            for (int reg = 0; reg < 4; reg++) {
                int m = m0 + wm + mi * 16 + quad * 4 + reg;
                int n = n0 + wn + ni * 16 + r16;
                float val = acc[mi][ni][reg];
                if constexpr (EPI == 0) {
                    val += bias[n] + ((const float*)resid)[(size_t)m * N + n];
                    ((bf16_t*)o0)[(size_t)m * N + n] = __float2bfloat16(val);
                } else if constexpr (EPI == 1) {
                    val = fmaxf(val + bias[n], 0.f);
                    ((bf16_t*)o0)[(size_t)m * N + n] = __float2bfloat16(val);
                } else if constexpr (EPI == 2) {
                    val += bias[n] + tof(((const bf16_t*)resid)[(size_t)m * N + n]);
                    ((float*)o0)[(size_t)m * N + n] = val;
                } else if constexpr (EPI == 4) {
                    atomicAdd(&((float*)o0)[(size_t)m * N + n], val);
                } else {
                    int mat = n / 384;
                    int nr  = n - mat * 384;
                    int head = nr >> 6, d = nr & 63;
                    int b = m >> 11, t = m & 2047;
                    int bh = b * HH + head;
                    bf16_t bv = __float2bfloat16(val);
                    if (mat == 0)      ((bf16_t*)o0)[(size_t)(bh * TT + t) * HS + d] = bv;
                    else if (mat == 1) ((bf16_t*)o1)[(size_t)(bh * TT + t) * HS + d] = bv;
                    else               ((bf16_t*)o2)[(size_t)(bh * HS + d) * VST + t] = bv;
                }
            }
}

// ---------------- colsum partial: XCD-swizzled 1D grid; K-tile LDS-staged (R15-proven) ----------------
__global__ __launch_bounds__(256) void colsum_kernel(const bf16_t* __restrict__ qbf,
                                                     const bf16_t* __restrict__ kbf,
                                                     float* __restrict__ colsum) {
    int id = blockIdx.x;
    int bh = (id & 7) + 8 * ((id >> 3) % 3);
    int rem = (id >> 3) / 3;
    int stile = rem & 31, z = rem >> 5;
    if (stile + z * 8 > 31) return;
    int s0 = stile * 64;
    const int lane = threadIdx.x & 63, wave = threadIdx.x >> 6;
    const int r16 = lane & 15, quad = lane >> 4;
    __shared__ bf16_t Ksh[64][72];
    __shared__ float csum[64];
    if (threadIdx.x < 64) csum[threadIdx.x] = 0.f;
    {
        const int srow = threadIdx.x >> 2, scol = (threadIdx.x & 3) << 4;
        const bf16_t* kp = kbf + (size_t)(bh * TT + s0 + srow) * HS + scol;
        *(short8*)&Ksh[srow][scol]     = ld8(kp);
        *(short8*)&Ksh[srow][scol + 8] = ld8(kp + 8);
    }
    __syncthreads();
    short8 bfr[4][2];
#pragma unroll
    for (int ns = 0; ns < 4; ns++)
#pragma unroll
        for (int kk = 0; kk < 2; kk++)
            bfr[ns][kk] = *(const short8*)&Ksh[ns * 16 + r16][kk * 32 + quad * 8];
    float colacc[4] = {0.f, 0.f, 0.f, 0.f};
    for (int jj = wave; jj < 8; jj += 4) {
        int tt = stile + z * 8 + jj;
        if (tt > 31) break;
#pragma unroll
        for (int ms = 0; ms < 4; ms++) {
            const bf16_t* qp = qbf + (size_t)(bh * TT + tt * 64 + ms * 16 + r16) * HS + quad * 8;
            short8 a0 = ld8(qp);
            short8 a1 = ld8(qp + 32);
#pragma unroll
            for (int ns = 0; ns < 4; ns++) {
                f32x4 sacc = {0.f, 0.f, 0.f, 0.f};
                sacc = MFMA(a0, bfr[ns][0], sacc);
                sacc = MFMA(a1, bfr[ns][1], sacc);
#pragma unroll
                for (int reg = 0; reg < 4; reg++) {
                    int t = tt * 64 + ms * 16 + quad * 4 + reg;
                    int s = s0 + ns * 16 + r16;
                    if (s <= t) colacc[ns] += __expf(sacc[reg] * SCALE);
                }
            }
        }
    }
#pragma unroll
    for (int ns = 0; ns < 4; ns++) atomicAdd(&csum[ns * 16 + r16], colacc[ns]);
    __syncthreads();
    if (threadIdx.x < 64) atomicAdd(&colsum[bh * TT + s0 + threadIdx.x], csum[threadIdx.x]);
}

// ---------------- attention partial: R18 body + log-space normalization + mask skip ----------------
__global__ __launch_bounds__(256) void attn_part_kernel(const bf16_t* __restrict__ qbf,
                                                        const bf16_t* __restrict__ kbf,
                                                        const bf16_t* __restrict__ vst,
                                                        const float* __restrict__ colsum,
                                                        float* __restrict__ attnf) {
    int id = blockIdx.x;
    int bh = (id & 7) + 8 * ((id >> 3) % 3);
    int rem = (id >> 3) / 3;
    int ttile2 = rem & 15, z = rem >> 4;
    int sbeg = z * 8;
    int last = 2 * ttile2 + 1;              // highest s-tile with any s <= t
    if (sbeg > last) return;
    int send = last + 1 < sbeg + 8 ? last + 1 : sbeg + 8;
    int t0 = ttile2 * 128;
    const int lane = threadIdx.x & 63, wave = threadIdx.x >> 6;
    const int r16 = lane & 15, quad = lane >> 4;
    __shared__ bf16_t Ksh[64][72];
    __shared__ bf16_t Vsh[64][72];
    __shared__ bf16_t El[128][72];
    __shared__ float Lcs[64];              // log(colsum) for this s-tile
    const int srow = threadIdx.x >> 2;
    const int scol = (threadIdx.x & 3) << 4;
    f32x4 zero = {0.f, 0.f, 0.f, 0.f};
    f32x4 oacc[2][4];
#pragma unroll
    for (int mi = 0; mi < 2; mi++)
#pragma unroll
        for (int ns = 0; ns < 4; ns++) oacc[mi][ns] = zero;
    short8 qa[2][2];
#pragma unroll
    for (int mi = 0; mi < 2; mi++) {
        const bf16_t* qp = qbf + (size_t)(bh * TT + t0 + wave * 32 + mi * 16 + r16) * HS + quad * 8;
        qa[mi][0] = ld8(qp);
        qa[mi][1] = ld8(qp + 32);
    }
    for (int st = sbeg; st < send; st++) {
        int s0 = st * 64;
        {
            const bf16_t* kp = kbf + (size_t)(bh * TT + s0 + srow) * HS + scol;
            short8 k0 = ld8(kp);
            short8 k1 = ld8(kp + 8);
            const bf16_t* vp = vst + (size_t)(bh * HS + srow) * VST + s0 + scol;
            short8 v0 = ld8(vp);
            short8 v1 = ld8(vp + 8);
            *(short8*)&Ksh[srow][scol]     = k0;
            *(short8*)&Ksh[srow][scol + 8] = k1;
            *(short8*)&Vsh[srow][scol]     = v0;
            *(short8*)&Vsh[srow][scol + 8] = v1;
            if (threadIdx.x < 64)
                Lcs[threadIdx.x] = __logf(colsum[bh * TT + s0 + threadIdx.x]);
        }
        __syncthreads();
#pragma unroll
        for (int mi = 0; mi < 2; mi++)
#pragma unroll
            for (int ns = 0; ns < 4; ns++) {
                float lc = Lcs[ns * 16 + r16];
                f32x4 sacc = zero;
                sacc = MFMA(qa[mi][0], *(const short8*)&Ksh[ns * 16 + r16][quad * 8], sacc);
                sacc = MFMA(qa[mi][1], *(const short8*)&Ksh[ns * 16 + r16][32 + quad * 8], sacc);
                // E = exp(S*SCALE - log(colsum)) — division folded into the mad
                if (s0 + ns * 16 + 15 <= t0 + wave * 32 + mi * 16) {
                    // tile strictly below diagonal: no mask needed
#pragma unroll
                    for (int reg = 0; reg < 4; reg++) {
                        float e = __expf(sacc[reg] * SCALE - lc);
                        El[wave * 32 + mi * 16 + quad * 4 + reg][ns * 16 + r16] = __float2bfloat16(e);
                    }
                } else {
#pragma unroll
                    for (int reg = 0; reg < 4; reg++) {
                        int t = t0 + wave * 32 + mi * 16 + quad * 4 + reg;
                        int s = s0 + ns * 16 + r16;
                        float e = (s <= t) ? __expf(sacc[reg] * SCALE - lc) : 0.f;
                        El[wave * 32 + mi * 16 + quad * 4 + reg][ns * 16 + r16] = __float2bfloat16(e);
                    }
                }
            }
#pragma unroll
        for (int mi = 0; mi < 2; mi++)
#pragma unroll
            for (int ks = 0; ks < 2; ks++) {
                short8 ea = ld8(&El[wave * 32 + mi * 16 + r16][ks * 32 + quad * 8]);
#pragma unroll
                for (int ns = 0; ns < 4; ns++) {
                    short8 vb = *(const short8*)&Vsh[ns * 16 + r16][ks * 32 + quad * 8];
                    oacc[mi][ns] = MFMA(ea, vb, oacc[mi][ns]);
                }
            }
        __syncthreads();
    }
    int b = bh / HH, head = bh - b * HH;
#pragma unroll
    for (int mi = 0; mi < 2; mi++)
#pragma unroll
        for (int ns = 0; ns < 4; ns++)
#pragma unroll
            for (int reg = 0; reg < 4; reg++) {
                int t = t0 + wave * 32 + mi * 16 + quad * 4 + reg;
                int d = ns * 16 + r16;
                atomicAdd(&attnf[(size_t)(b * TT + t) * CC + head * HS + d], oacc[mi][ns][reg]);
            }
}

extern "C" void kernel_launch(void* const* d_in, const int* in_sizes, int n_in,
                              void* d_out, int out_size, void* d_ws, size_t ws_size,
                              hipStream_t stream) {
    const float* x      = (const float*)d_in[0];
    const float* wq     = (const float*)d_in[1];
    const float* wk     = (const float*)d_in[2];
    const float* wv     = (const float*)d_in[3];
    const float* w_proj = (const float*)d_in[4];
    const float* b_proj = (const float*)d_in[5];
    const float* w1     = (const float*)d_in[6];
    const float* b1     = (const float*)d_in[7];
    const float* w2     = (const float*)d_in[8];
    const float* b2     = (const float*)d_in[9];
    const float* g1     = (const float*)d_in[10];
    const float* be1    = (const float*)d_in[11];
    const float* g2     = (const float*)d_in[12];
    const float* be2    = (const float*)d_in[13];
    float* out = (float*)d_out;

    // ---- overlaid workspace plan, total 28,803,072 B (proven footprint) ----
    char* p = (char*)d_ws;
    auto alloc = [&](size_t bytes) {
        void* r = (void*)p;
        p += (bytes + 255) & ~(size_t)255;
        return r;
    };
    const size_t ACT  = (size_t)BT * CC * 2;      // 6291456 B
    bf16_t* wqt    = (bf16_t*)alloc(HH * HS * CC * 2);   // wall base (wq|wk|wv contiguous)
    bf16_t* wkt    = (bf16_t*)alloc(HH * HS * CC * 2);
    bf16_t* wvt    = (bf16_t*)alloc(HH * HS * CC * 2);
    bf16_t* wpt    = (bf16_t*)alloc(CC * CC * 2);
    bf16_t* w1t    = (bf16_t*)alloc((size_t)C4 * CC * 2);
    bf16_t* w2t    = (bf16_t*)alloc((size_t)CC * C4 * 2);
    char* slotA = (char*)alloc(ACT);                       // h -> h2
    char* slotB = (char*)alloc(2 * ACT);                   // q|k -> f1 chunk
    char* slotC = (char*)alloc((size_t)24 * HS * VST * 2); // v^T padded -> x1b

    bf16_t* h_bf    = (bf16_t*)slotA;
    bf16_t* h2_bf   = (bf16_t*)slotA;
    bf16_t* q_bf    = (bf16_t*)slotB;
    bf16_t* k_bf    = (bf16_t*)(slotB + ACT);
    bf16_t* f1      = (bf16_t*)slotB;
    bf16_t* v_bf    = (bf16_t*)slotC;
    bf16_t* x1b     = (bf16_t*)slotC;
    float* colsum   = (float*)wqt;            // overlays wall (dead after qkv)
    float* attn_f   = (float*)d_out;          // fp32 attn accumulator (dead after proj)
    (void)wkt; (void)wvt;

    // 1. prep: LDS-tiled weight transposes + zero attn_f (one launch, 624 blocks)
    prep_kernel<<<624, 256, 0, stream>>>(
        wq, wk, wv, w_proj, w1, w2, wqt, wpt, w1t, w2t, attn_f);
    // 2. LN1
    ln_kernel<float, false><<<BT/4, 256, 0, stream>>>(x, g1, be1, h_bf, nullptr, nullptr);
    // 3. fused QKV: h(8192x384) @ wall^T(1152x384) -> q, k, v^T (unscaled)
    gemm128_kernel<CC, 3><<<dim3(BT/128, 9), 256, 0, stream>>>(
        h_bf, wqt, nullptr, nullptr, q_bf, k_bf, v_bf, 1152);
    // 4. zero colsum (wall dead), column sums — XCD-swizzled 1D grid
    zinit_kernel<<<48, 256, 0, stream>>>(colsum, 24*TT/4);
    colsum_kernel<<<3072, 256, 0, stream>>>(q_bf, k_bf, colsum);
    // 5. attention — 128-row t-tiles, XCD-swizzled, log-normalized E, atomic accum
    attn_part_kernel<<<1536, 256, 0, stream>>>(q_bf, k_bf, v_bf, colsum, attn_f);
    // 6. proj (A = fp32 accumulator, converted in-staging) + bias + resid(x) -> x1b
    gemm128_kernel<CC, 0, true><<<dim3(BT/128, CC/128), 256, 0, stream>>>(
        attn_f, wpt, b_proj, x, x1b, nullptr, nullptr, CC);
    // 7. LN2 (bf16 input) -> h2; ALSO writes d_out init = b2 + x1b (mlp2 base)
    ln_kernel<bf16_t, true><<<BT/4, 256, 0, stream>>>(x1b, g2, be2, h2_bf, b2, out);
    // 8+9. MLP in 2 row-chunks of 4096; mlp2 split-K x4 atomic into d_out
    for (int c = 0; c < 2; c++) {
        size_t m0 = (size_t)c * 4096;
        gemm128_kernel<CC, 1><<<dim3(4096/128, C4/128), 256, 0, stream>>>(
            h2_bf + m0 * CC, w1t, b1, nullptr, f1, nullptr, nullptr, C4);
        gemm128_kernel<C4, 4><<<dim3(4096/128, CC/128, 4), 256, 0, stream>>>(
            f1, w2t, nullptr, nullptr, out + m0 * CC, nullptr, nullptr, CC);
    }
}

// Round 20
// 286.849 us; speedup vs baseline: 1.0445x; 1.0445x over previous
//
#include <hip/hip_runtime.h>
#include <hip/hip_bf16.h>

// Transformer block: B=4 T=2048 C=384 H=6 HS=64.
// Reference softmax is over the QUERY axis -> w[t,s] = exp(S[t,s])/colsum[s],
// colsum[s] = sum_{t>=s} exp(S[t,s]).  Pipeline: colsum pass, then out = E @ V
// with E divided by colsum in-kernel (LDS-cached reciprocals).
//
// R20:
//  - attn: reverted byte-identical to R18 (47.5us proven). R19's log-space trim
//    cut VALU but +4 VGPR -> occupancy 23.8->19.3 -> 51.7us. Attn is TLP-bound.
//  - gemm128: BK 32 -> 64. At BK=32+prefetch the per-iteration load-wait
//    (~450cyc) exceeds the MFMA phase (~150cyc); BK=64 doubles MFMA per barrier
//    round and halves the wait count. LDS 20.5->36.9KB is free (grids are
//    <=2.25 blocks/CU, grid-limited). Pad stays 8 (2-way bank alias = free).
// WS total 28,803,072 B (proven footprint).

#define BB 4
#define TT 2048
#define CC 384
#define HH 6
#define HS 64
#define BT 8192
#define C4 1536
#define VST 2080              // padded V^T leading dim (elements): 4160B rows
#define SCALE 0.05103103630798288f   // 384^-0.5

typedef __attribute__((ext_vector_type(8))) short short8;   // 8 x bf16
typedef __attribute__((ext_vector_type(4))) float f32x4;
typedef __hip_bfloat16 bf16_t;

__device__ inline short8 ld8(const bf16_t* p) { return *reinterpret_cast<const short8*>(p); }
__device__ inline float tof(float v) { return v; }
__device__ inline float tof(bf16_t v) { return __bfloat162float(v); }
__device__ inline short8 cv8(const float* p) {
    f32x4 lo = *(const f32x4*)p;
    f32x4 hi = *(const f32x4*)(p + 4);
    short8 r;
#pragma unroll
    for (int i = 0; i < 4; i++) {
        bf16_t a = __float2bfloat16(lo[i]);
        bf16_t b = __float2bfloat16(hi[i]);
        r[i]     = *reinterpret_cast<short*>(&a);
        r[i + 4] = *reinterpret_cast<short*>(&b);
    }
    return r;
}
#define MFMA(a, b, c) __builtin_amdgcn_mfma_f32_16x16x32_bf16(a, b, c, 0, 0, 0)

// ---------------- zero-init ----------------
__global__ __launch_bounds__(256) void zinit_kernel(float* __restrict__ p, int n4) {
    int i = blockIdx.x * 256 + threadIdx.x;
    if (i < n4) ((f32x4*)p)[i] = (f32x4){0.f, 0.f, 0.f, 0.f};
}

// ---------------- prep: LDS-tiled 64x64 transposes (R16-proven) + attn_f zero ----------------
#define RW  147456          // per qkv matrix element count (6 heads x 384 x 64)
__global__ __launch_bounds__(256) void prep_kernel(const float* __restrict__ wq,
                                                   const float* __restrict__ wk,
                                                   const float* __restrict__ wv,
                                                   const float* __restrict__ wproj,
                                                   const float* __restrict__ w1,
                                                   const float* __restrict__ w2,
                                                   bf16_t* __restrict__ wall,   // wqt|wkt|wvt
                                                   bf16_t* __restrict__ wpt,
                                                   bf16_t* __restrict__ w1t,
                                                   bf16_t* __restrict__ w2t,
                                                   float* __restrict__ attnf) {
    int id = blockIdx.x;
    int tid = threadIdx.x;
    if (id >= 432) {                       // zero range: 192 blocks
        int base = (id - 432) * 256 + tid; // 0..49151
        f32x4 z = {0.f, 0.f, 0.f, 0.f};
#pragma unroll
        for (int k = 0; k < 16; k++)
            ((f32x4*)attnf)[base + k * 49152] = z;
        return;
    }
    const float* src; bf16_t* dst; int R, C, t;
    if (id < 108) {                        // wq/wk/wv: per head R=384, C=64
        int m = id / 36, r = id - m * 36;
        src = (m == 0 ? wq : (m == 1 ? wk : wv));
        dst = wall + m * RW;
        int b = r / 6; t = r - b * 6;
        src += b * 24576; dst += b * 24576;
        R = 384; C = 64;
    } else if (id < 144) { src = wproj; dst = wpt; t = id - 108; R = 384;  C = 384; }
    else if (id < 288)   { src = w1;    dst = w1t; t = id - 144; R = 384;  C = 1536; }
    else                 { src = w2;    dst = w2t; t = id - 288; R = 1536; C = 384; }
    int tiles_r = R >> 6;
    int tr = t % tiles_r, tc = t / tiles_r;
    __shared__ float Tsh[64][65];
    const int rr = tid >> 4;               // 0..15
    const int cc = (tid & 15) * 4;         // 0..60
#pragma unroll
    for (int i = 0; i < 4; i++) {
        int row = tr * 64 + rr + i * 16;
        f32x4 v = *(const f32x4*)(src + (size_t)row * C + tc * 64 + cc);
#pragma unroll
        for (int j = 0; j < 4; j++) Tsh[rr + i * 16][cc + j] = v[j];
    }
    __syncthreads();
#pragma unroll
    for (int i = 0; i < 4; i++) {
        int cl = rr + i * 16;              // out-row (n) local index
        ushort4 o;
        bf16_t b0 = __float2bfloat16(Tsh[cc + 0][cl]);
        bf16_t b1 = __float2bfloat16(Tsh[cc + 1][cl]);
        bf16_t b2v = __float2bfloat16(Tsh[cc + 2][cl]);
        bf16_t b3 = __float2bfloat16(Tsh[cc + 3][cl]);
        o.x = *reinterpret_cast<unsigned short*>(&b0);
        o.y = *reinterpret_cast<unsigned short*>(&b1);
        o.z = *reinterpret_cast<unsigned short*>(&b2v);
        o.w = *reinterpret_cast<unsigned short*>(&b3);
        *(ushort4*)(dst + (size_t)(tc * 64 + cl) * R + tr * 64 + cc) = o;
    }
}

// ---------------- LayerNorm: one wave per row of 384; input fp32 or bf16 ----------------
// INIT: also write oinit[m][c] = bias2[c] + raw x value (mlp2 split-K base).
template <typename T, bool INIT>
__global__ __launch_bounds__(256) void ln_kernel(const T* __restrict__ x,
                                                 const float* __restrict__ g,
                                                 const float* __restrict__ be,
                                                 bf16_t* __restrict__ out,
                                                 const float* __restrict__ bias2,
                                                 float* __restrict__ oinit) {
    int wave = threadIdx.x >> 6, lane = threadIdx.x & 63;
    int row = blockIdx.x * 4 + wave;
    const T* xr = x + (size_t)row * CC;
    float v[6];
    float s = 0.f;
#pragma unroll
    for (int i = 0; i < 6; i++) { v[i] = tof(xr[lane + i * 64]); s += v[i]; }
#pragma unroll
    for (int off = 32; off > 0; off >>= 1) s += __shfl_xor(s, off, 64);
    float mean = s * (1.f / 384.f);
    float s2 = 0.f;
#pragma unroll
    for (int i = 0; i < 6; i++) { float d = v[i] - mean; s2 += d * d; }
#pragma unroll
    for (int off = 32; off > 0; off >>= 1) s2 += __shfl_xor(s2, off, 64);
    float rstd = rsqrtf(s2 * (1.f / 384.f) + 1e-5f);
    bf16_t* orow = out + (size_t)row * CC;
#pragma unroll
    for (int i = 0; i < 6; i++) {
        int c = lane + i * 64;
        orow[c] = __float2bfloat16((v[i] - mean) * rstd * g[c] + be[c]);
        if constexpr (INIT) oinit[(size_t)row * CC + c] = bias2[c] + v[i];
    }
}

// ---------------- 128x128-tile GEMM, BK=64, LDS-staged, software-pipelined (R20). ----------------
// EPI: 0 = +bias +fp32 resid -> bf16; 1 = +bias relu -> bf16; 2 = +bias +bf16 resid -> fp32;
//      3 = qkv scatter; 4 = split-K: blockIdx.z picks K range [z*KDIM/4, +KDIM/4), fp32 atomicAdd.
template <int KDIM, int EPI, bool AF32 = false>
__global__ __launch_bounds__(256) void gemm128_kernel(const void* __restrict__ A,
                                                      const bf16_t* __restrict__ Bt,
                                                      const float* __restrict__ bias,
                                                      const void* __restrict__ resid,
                                                      void* __restrict__ o0,
                                                      void* __restrict__ o1,
                                                      void* __restrict__ o2, int N) {
    const int m0 = blockIdx.x * 128, n0 = blockIdx.y * 128;
    const int tid = threadIdx.x;
    const int lane = tid & 63, wave = tid >> 6;
    const int r16 = lane & 15, quad = lane >> 4;
    const int wm = (wave >> 1) * 64, wn = (wave & 1) * 64;
    __shared__ bf16_t Ash[128][72];   // 64 cols + 8 pad (2-way bank alias = free)
    __shared__ bf16_t Bsh[128][72];
    f32x4 zero = {0.f, 0.f, 0.f, 0.f};
    f32x4 acc[4][4];
#pragma unroll
    for (int i = 0; i < 4; i++)
#pragma unroll
        for (int j = 0; j < 4; j++) acc[i][j] = zero;
    const int srow = tid >> 2;             // 64 rows, 4 threads/row
    const int scol = (tid & 3) * 16;       // 16 elems = 2x16B per thread
    int kbeg = 0, kend = KDIM;
    if constexpr (EPI == 4) { kbeg = blockIdx.z * (KDIM / 4); kend = kbeg + KDIM / 4; }
    short8 pa[2][2], pb[2][2];             // [row half][col seg]
    auto loadAB = [&](int k0) {
        if constexpr (AF32) {
            const float* Ag = (const float*)A + (size_t)(m0 + srow) * KDIM + k0 + scol;
            pa[0][0] = cv8(Ag);
            pa[0][1] = cv8(Ag + 8);
            pa[1][0] = cv8(Ag + (size_t)64 * KDIM);
            pa[1][1] = cv8(Ag + (size_t)64 * KDIM + 8);
        } else {
            const bf16_t* Ag = (const bf16_t*)A + (size_t)(m0 + srow) * KDIM + k0 + scol;
            pa[0][0] = ld8(Ag);
            pa[0][1] = ld8(Ag + 8);
            pa[1][0] = ld8(Ag + (size_t)64 * KDIM);
            pa[1][1] = ld8(Ag + (size_t)64 * KDIM + 8);
        }
        const bf16_t* Bg = Bt + (size_t)(n0 + srow) * KDIM + k0 + scol;
        pb[0][0] = ld8(Bg);
        pb[0][1] = ld8(Bg + 8);
        pb[1][0] = ld8(Bg + (size_t)64 * KDIM);
        pb[1][1] = ld8(Bg + (size_t)64 * KDIM + 8);
    };
    loadAB(kbeg);
    for (int k0 = kbeg; k0 < kend; k0 += 64) {
        *(short8*)&Ash[srow][scol]           = pa[0][0];
        *(short8*)&Ash[srow][scol + 8]       = pa[0][1];
        *(short8*)&Ash[64 + srow][scol]      = pa[1][0];
        *(short8*)&Ash[64 + srow][scol + 8]  = pa[1][1];
        *(short8*)&Bsh[srow][scol]           = pb[0][0];
        *(short8*)&Bsh[srow][scol + 8]       = pb[0][1];
        *(short8*)&Bsh[64 + srow][scol]      = pb[1][0];
        *(short8*)&Bsh[64 + srow][scol + 8]  = pb[1][1];
        __syncthreads();
        // prefetch next k-tile (clamped) — latency hidden behind the MFMA phase
        loadAB(k0 + 64 < kend ? k0 + 64 : kbeg);
#pragma unroll
        for (int h = 0; h < 2; h++) {
            short8 af[4], bfr[4];
#pragma unroll
            for (int i = 0; i < 4; i++) af[i]  = *(const short8*)&Ash[wm + i * 16 + r16][h * 32 + quad * 8];
#pragma unroll
            for (int i = 0; i < 4; i++) bfr[i] = *(const short8*)&Bsh[wn + i * 16 + r16][h * 32 + quad * 8];
#pragma unroll
            for (int mi = 0; mi < 4; mi++)
#pragma unroll
                for (int ni = 0; ni < 4; ni++)
                    acc[mi][ni] = MFMA(af[mi], bfr[ni], acc[mi][ni]);
        }
        __syncthreads();
    }
#pragma unroll
    for (int mi = 0; mi < 4; mi++)
#pragma unroll
        for (int ni = 0; ni < 4; ni++)
#pragma unroll
            for (int reg = 0; reg < 4; reg++) {
                int m = m0 + wm + mi * 16 + quad * 4 + reg;
                int n = n0 + wn + ni * 16 + r16;
                float val = acc[mi][ni][reg];
                if constexpr (EPI == 0) {
                    val += bias[n] + ((const float*)resid)[(size_t)m * N + n];
                    ((bf16_t*)o0)[(size_t)m * N + n] = __float2bfloat16(val);
                } else if constexpr (EPI == 1) {
                    val = fmaxf(val + bias[n], 0.f);
                    ((bf16_t*)o0)[(size_t)m * N + n] = __float2bfloat16(val);
                } else if constexpr (EPI == 2) {
                    val += bias[n] + tof(((const bf16_t*)resid)[(size_t)m * N + n]);
                    ((float*)o0)[(size_t)m * N + n] = val;
                } else if constexpr (EPI == 4) {
                    atomicAdd(&((float*)o0)[(size_t)m * N + n], val);
                } else {
                    int mat = n / 384;
                    int nr  = n - mat * 384;
                    int head = nr >> 6, d = nr & 63;
                    int b = m >> 11, t = m & 2047;
                    int bh = b * HH + head;
                    bf16_t bv = __float2bfloat16(val);
                    if (mat == 0)      ((bf16_t*)o0)[(size_t)(bh * TT + t) * HS + d] = bv;
                    else if (mat == 1) ((bf16_t*)o1)[(size_t)(bh * TT + t) * HS + d] = bv;
                    else               ((bf16_t*)o2)[(size_t)(bh * HS + d) * VST + t] = bv;
                }
            }
}

// ---------------- colsum partial: XCD-swizzled 1D grid; K-tile LDS-staged (R15-proven) ----------------
__global__ __launch_bounds__(256) void colsum_kernel(const bf16_t* __restrict__ qbf,
                                                     const bf16_t* __restrict__ kbf,
                                                     float* __restrict__ colsum) {
    int id = blockIdx.x;
    int bh = (id & 7) + 8 * ((id >> 3) % 3);
    int rem = (id >> 3) / 3;
    int stile = rem & 31, z = rem >> 5;
    if (stile + z * 8 > 31) return;
    int s0 = stile * 64;
    const int lane = threadIdx.x & 63, wave = threadIdx.x >> 6;
    const int r16 = lane & 15, quad = lane >> 4;
    __shared__ bf16_t Ksh[64][72];
    __shared__ float csum[64];
    if (threadIdx.x < 64) csum[threadIdx.x] = 0.f;
    {
        const int srow = threadIdx.x >> 2, scol = (threadIdx.x & 3) << 4;
        const bf16_t* kp = kbf + (size_t)(bh * TT + s0 + srow) * HS + scol;
        *(short8*)&Ksh[srow][scol]     = ld8(kp);
        *(short8*)&Ksh[srow][scol + 8] = ld8(kp + 8);
    }
    __syncthreads();
    short8 bfr[4][2];
#pragma unroll
    for (int ns = 0; ns < 4; ns++)
#pragma unroll
        for (int kk = 0; kk < 2; kk++)
            bfr[ns][kk] = *(const short8*)&Ksh[ns * 16 + r16][kk * 32 + quad * 8];
    float colacc[4] = {0.f, 0.f, 0.f, 0.f};
    for (int jj = wave; jj < 8; jj += 4) {
        int tt = stile + z * 8 + jj;
        if (tt > 31) break;
#pragma unroll
        for (int ms = 0; ms < 4; ms++) {
            const bf16_t* qp = qbf + (size_t)(bh * TT + tt * 64 + ms * 16 + r16) * HS + quad * 8;
            short8 a0 = ld8(qp);
            short8 a1 = ld8(qp + 32);
#pragma unroll
            for (int ns = 0; ns < 4; ns++) {
                f32x4 sacc = {0.f, 0.f, 0.f, 0.f};
                sacc = MFMA(a0, bfr[ns][0], sacc);
                sacc = MFMA(a1, bfr[ns][1], sacc);
#pragma unroll
                for (int reg = 0; reg < 4; reg++) {
                    int t = tt * 64 + ms * 16 + quad * 4 + reg;
                    int s = s0 + ns * 16 + r16;
                    if (s <= t) colacc[ns] += __expf(sacc[reg] * SCALE);
                }
            }
        }
    }
#pragma unroll
    for (int ns = 0; ns < 4; ns++) atomicAdd(&csum[ns * 16 + r16], colacc[ns]);
    __syncthreads();
    if (threadIdx.x < 64) atomicAdd(&colsum[bh * TT + s0 + threadIdx.x], csum[threadIdx.x]);
}

// ---------------- attention partial: R18-proven body (128-row t-tiles, XCD-swizzled) ----------------
__global__ __launch_bounds__(256) void attn_part_kernel(const bf16_t* __restrict__ qbf,
                                                        const bf16_t* __restrict__ kbf,
                                                        const bf16_t* __restrict__ vst,
                                                        const float* __restrict__ colsum,
                                                        float* __restrict__ attnf) {
    int id = blockIdx.x;
    int bh = (id & 7) + 8 * ((id >> 3) % 3);
    int rem = (id >> 3) / 3;
    int ttile2 = rem & 15, z = rem >> 4;
    int sbeg = z * 8;
    int last = 2 * ttile2 + 1;              // highest s-tile with any s <= t
    if (sbeg > last) return;
    int send = last + 1 < sbeg + 8 ? last + 1 : sbeg + 8;
    int t0 = ttile2 * 128;
    const int lane = threadIdx.x & 63, wave = threadIdx.x >> 6;
    const int r16 = lane & 15, quad = lane >> 4;
    __shared__ bf16_t Ksh[64][72];
    __shared__ bf16_t Vsh[64][72];
    __shared__ bf16_t El[128][72];
    __shared__ float Crc[64];
    const int srow = threadIdx.x >> 2;
    const int scol = (threadIdx.x & 3) << 4;
    f32x4 zero = {0.f, 0.f, 0.f, 0.f};
    f32x4 oacc[2][4];
#pragma unroll
    for (int mi = 0; mi < 2; mi++)
#pragma unroll
        for (int ns = 0; ns < 4; ns++) oacc[mi][ns] = zero;
    short8 qa[2][2];
#pragma unroll
    for (int mi = 0; mi < 2; mi++) {
        const bf16_t* qp = qbf + (size_t)(bh * TT + t0 + wave * 32 + mi * 16 + r16) * HS + quad * 8;
        qa[mi][0] = ld8(qp);
        qa[mi][1] = ld8(qp + 32);
    }
    for (int st = sbeg; st < send; st++) {
        int s0 = st * 64;
        {
            const bf16_t* kp = kbf + (size_t)(bh * TT + s0 + srow) * HS + scol;
            short8 k0 = ld8(kp);
            short8 k1 = ld8(kp + 8);
            const bf16_t* vp = vst + (size_t)(bh * HS + srow) * VST + s0 + scol;
            short8 v0 = ld8(vp);
            short8 v1 = ld8(vp + 8);
            *(short8*)&Ksh[srow][scol]     = k0;
            *(short8*)&Ksh[srow][scol + 8] = k1;
            *(short8*)&Vsh[srow][scol]     = v0;
            *(short8*)&Vsh[srow][scol + 8] = v1;
            if (threadIdx.x < 64)
                Crc[threadIdx.x] = 1.0f / colsum[bh * TT + s0 + threadIdx.x];
        }
        __syncthreads();
#pragma unroll
        for (int mi = 0; mi < 2; mi++)
#pragma unroll
            for (int ns = 0; ns < 4; ns++) {
                float rc = Crc[ns * 16 + r16];
                f32x4 sacc = zero;
                sacc = MFMA(qa[mi][0], *(const short8*)&Ksh[ns * 16 + r16][quad * 8], sacc);
                sacc = MFMA(qa[mi][1], *(const short8*)&Ksh[ns * 16 + r16][32 + quad * 8], sacc);
#pragma unroll
                for (int reg = 0; reg < 4; reg++) {
                    int t = t0 + wave * 32 + mi * 16 + quad * 4 + reg;
                    int s = s0 + ns * 16 + r16;
                    float e = (s <= t) ? __expf(sacc[reg] * SCALE) * rc : 0.f;
                    El[wave * 32 + mi * 16 + quad * 4 + reg][ns * 16 + r16] = __float2bfloat16(e);
                }
            }
#pragma unroll
        for (int mi = 0; mi < 2; mi++)
#pragma unroll
            for (int ks = 0; ks < 2; ks++) {
                short8 ea = ld8(&El[wave * 32 + mi * 16 + r16][ks * 32 + quad * 8]);
#pragma unroll
                for (int ns = 0; ns < 4; ns++) {
                    short8 vb = *(const short8*)&Vsh[ns * 16 + r16][ks * 32 + quad * 8];
                    oacc[mi][ns] = MFMA(ea, vb, oacc[mi][ns]);
                }
            }
        __syncthreads();
    }
    int b = bh / HH, head = bh - b * HH;
#pragma unroll
    for (int mi = 0; mi < 2; mi++)
#pragma unroll
        for (int ns = 0; ns < 4; ns++)
#pragma unroll
            for (int reg = 0; reg < 4; reg++) {
                int t = t0 + wave * 32 + mi * 16 + quad * 4 + reg;
                int d = ns * 16 + r16;
                atomicAdd(&attnf[(size_t)(b * TT + t) * CC + head * HS + d], oacc[mi][ns][reg]);
            }
}

extern "C" void kernel_launch(void* const* d_in, const int* in_sizes, int n_in,
                              void* d_out, int out_size, void* d_ws, size_t ws_size,
                              hipStream_t stream) {
    const float* x      = (const float*)d_in[0];
    const float* wq     = (const float*)d_in[1];
    const float* wk     = (const float*)d_in[2];
    const float* wv     = (const float*)d_in[3];
    const float* w_proj = (const float*)d_in[4];
    const float* b_proj = (const float*)d_in[5];
    const float* w1     = (const float*)d_in[6];
    const float* b1     = (const float*)d_in[7];
    const float* w2     = (const float*)d_in[8];
    const float* b2     = (const float*)d_in[9];
    const float* g1     = (const float*)d_in[10];
    const float* be1    = (const float*)d_in[11];
    const float* g2     = (const float*)d_in[12];
    const float* be2    = (const float*)d_in[13];
    float* out = (float*)d_out;

    // ---- overlaid workspace plan, total 28,803,072 B (proven footprint) ----
    char* p = (char*)d_ws;
    auto alloc = [&](size_t bytes) {
        void* r = (void*)p;
        p += (bytes + 255) & ~(size_t)255;
        return r;
    };
    const size_t ACT  = (size_t)BT * CC * 2;      // 6291456 B
    bf16_t* wqt    = (bf16_t*)alloc(HH * HS * CC * 2);   // wall base (wq|wk|wv contiguous)
    bf16_t* wkt    = (bf16_t*)alloc(HH * HS * CC * 2);
    bf16_t* wvt    = (bf16_t*)alloc(HH * HS * CC * 2);
    bf16_t* wpt    = (bf16_t*)alloc(CC * CC * 2);
    bf16_t* w1t    = (bf16_t*)alloc((size_t)C4 * CC * 2);
    bf16_t* w2t    = (bf16_t*)alloc((size_t)CC * C4 * 2);
    char* slotA = (char*)alloc(ACT);                       // h -> h2
    char* slotB = (char*)alloc(2 * ACT);                   // q|k -> f1 chunk
    char* slotC = (char*)alloc((size_t)24 * HS * VST * 2); // v^T padded -> x1b

    bf16_t* h_bf    = (bf16_t*)slotA;
    bf16_t* h2_bf   = (bf16_t*)slotA;
    bf16_t* q_bf    = (bf16_t*)slotB;
    bf16_t* k_bf    = (bf16_t*)(slotB + ACT);
    bf16_t* f1      = (bf16_t*)slotB;
    bf16_t* v_bf    = (bf16_t*)slotC;
    bf16_t* x1b     = (bf16_t*)slotC;
    float* colsum   = (float*)wqt;            // overlays wall (dead after qkv)
    float* attn_f   = (float*)d_out;          // fp32 attn accumulator (dead after proj)
    (void)wkt; (void)wvt;

    // 1. prep: LDS-tiled weight transposes + zero attn_f (one launch, 624 blocks)
    prep_kernel<<<624, 256, 0, stream>>>(
        wq, wk, wv, w_proj, w1, w2, wqt, wpt, w1t, w2t, attn_f);
    // 2. LN1
    ln_kernel<float, false><<<BT/4, 256, 0, stream>>>(x, g1, be1, h_bf, nullptr, nullptr);
    // 3. fused QKV: h(8192x384) @ wall^T(1152x384) -> q, k, v^T (unscaled)
    gemm128_kernel<CC, 3><<<dim3(BT/128, 9), 256, 0, stream>>>(
        h_bf, wqt, nullptr, nullptr, q_bf, k_bf, v_bf, 1152);
    // 4. zero colsum (wall dead), column sums — XCD-swizzled 1D grid
    zinit_kernel<<<48, 256, 0, stream>>>(colsum, 24*TT/4);
    colsum_kernel<<<3072, 256, 0, stream>>>(q_bf, k_bf, colsum);
    // 5. attention — 128-row t-tiles, XCD-swizzled 1D grid, atomic accumulate
    attn_part_kernel<<<1536, 256, 0, stream>>>(q_bf, k_bf, v_bf, colsum, attn_f);
    // 6. proj (A = fp32 accumulator, converted in-staging) + bias + resid(x) -> x1b
    gemm128_kernel<CC, 0, true><<<dim3(BT/128, CC/128), 256, 0, stream>>>(
        attn_f, wpt, b_proj, x, x1b, nullptr, nullptr, CC);
    // 7. LN2 (bf16 input) -> h2; ALSO writes d_out init = b2 + x1b (mlp2 base)
    ln_kernel<bf16_t, true><<<BT/4, 256, 0, stream>>>(x1b, g2, be2, h2_bf, b2, out);
    // 8+9. MLP in 2 row-chunks of 4096; mlp2 split-K x4 atomic into d_out
    for (int c = 0; c < 2; c++) {
        size_t m0 = (size_t)c * 4096;
        gemm128_kernel<CC, 1><<<dim3(4096/128, C4/128), 256, 0, stream>>>(
            h2_bf + m0 * CC, w1t, b1, nullptr, f1, nullptr, nullptr, C4);
        gemm128_kernel<C4, 4><<<dim3(4096/128, CC/128, 4), 256, 0, stream>>>(
            f1, w2t, nullptr, nullptr, out + m0 * CC, nullptr, nullptr, CC);
    }
}